// Round 9
// baseline (177.400 us; speedup 1.0000x reference)
//
#include <hip/hip_runtime.h>

#define NB 8
#define NC 256
#define FH 64
#define FW 64
#define NS (FH * FW)          // 4096 spatial positions per batch
#define NSAMP 131072
#define MARGIN_F 12.0f

#define BUCKET_CAP NSAMP
#define GATHER_BLOCKS 2048    // one full-occupancy round
#define CHUNK 32              // records per cursor grab (1 per octet)

typedef float vfloat2 __attribute__((ext_vector_type(2)));

// ---------------------------------------------------------------------------
// fp8 e4m3 (OCP) pack via gfx950 HW converts.
// ---------------------------------------------------------------------------
__device__ __forceinline__ unsigned pack4_fp8(float f0, float f1, float f2, float f3)
{
    int r = __builtin_amdgcn_cvt_pk_fp8_f32(f0, f1, 0, false);  // bytes 0,1
    r     = __builtin_amdgcn_cvt_pk_fp8_f32(f2, f3, r, true);   // bytes 2,3
    return (unsigned)r;
}

// ---------------------------------------------------------------------------
// Kernel 1 (fused): z<16 -> transpose (B,C,S) fp32 -> (B,S,C) fp8 (verified
// since R5). z==16 -> bucket the 131072 samples by batch index into per-
// bucket record arrays (verified since R7). The two halves are independent;
// bucketing hides inside the transpose's memory time.
// ---------------------------------------------------------------------------
__global__ __launch_bounds__(256) void transpose_bucket(
    const float* __restrict__ in0, const float* __restrict__ in1,
    unsigned char* __restrict__ out0, unsigned char* __restrict__ out1,
    const int*  __restrict__ batch_idx,
    const int2* __restrict__ anchor_yx,
    const int2* __restrict__ pos_yx,
    const int2* __restrict__ neg_yx,
    uint4* __restrict__ recs,
    unsigned* __restrict__ counts)
{
    __shared__ float tile[64][65];
    const int t = threadIdx.x;

    if (blockIdx.z < 16) {
        const int which = blockIdx.z >> 3;
        const int b     = blockIdx.z & 7;
        const float* __restrict__ in  = which ? in1 : in0;
        unsigned char* __restrict__ out = which ? out1 : out0;

        const int s0 = blockIdx.x * 64;
        const int c0 = blockIdx.y * 64;

        const float* __restrict__ inb  = in  + (size_t)b * NC * NS;
        unsigned char* __restrict__ outb = out + (size_t)b * NS * NC;

        const int g   = t >> 4;          // 0..15
        const int sl4 = (t & 15) << 2;   // 0,4,...,60
#pragma unroll
        for (int pass = 0; pass < 4; ++pass) {
            const int cl = pass * 16 + g;
            const float4 v = *(const float4*)&inb[(size_t)(c0 + cl) * NS + (s0 + sl4)];
            tile[sl4 + 0][cl] = v.x;
            tile[sl4 + 1][cl] = v.y;
            tile[sl4 + 2][cl] = v.z;
            tile[sl4 + 3][cl] = v.w;
        }
        __syncthreads();

        const int cl4 = (t & 15) << 2;
#pragma unroll
        for (int pass = 0; pass < 4; ++pass) {
            const int sl = pass * 16 + (t >> 4);
            const unsigned w = pack4_fp8(tile[sl][cl4 + 0], tile[sl][cl4 + 1],
                                         tile[sl][cl4 + 2], tile[sl][cl4 + 3]);
            *(unsigned*)&outb[(size_t)(s0 + sl) * NC + (c0 + cl4)] = w;
        }
        return;
    }

    // ---- bucket half: 256 blocks (x:0..63, y:0..3), 2 samples/thread ----
    __shared__ unsigned hist[8], base[8];
    const int blk = blockIdx.x + 64 * blockIdx.y;   // 0..255

    if (t < 8) hist[t] = 0;
    __syncthreads();

    int   bb[2];
    unsigned rank[2];
    uint4 rec[2];
#pragma unroll
    for (int k = 0; k < 2; ++k) {
        const int i = blk * 512 + k * 256 + t;
        const int  b  = batch_idx[i];
        const int2 ay = anchor_yx[i];
        const int2 py = pos_yx[i];
        const int2 ny = neg_yx[i];
        rec[k] = make_uint4((unsigned)(b * NS + ay.x * FW + ay.y),
                            (unsigned)(b * NS + py.x * FW + py.y),
                            (unsigned)(b * NS + ny.x * FW + ny.y), 0u);
        bb[k]   = b;
        rank[k] = atomicAdd(&hist[b], 1u);          // LDS atomic
    }
    __syncthreads();
    if (t < 8) base[t] = atomicAdd(&counts[t], hist[t]);
    __syncthreads();
#pragma unroll
    for (int k = 0; k < 2; ++k)
        recs[(size_t)bb[k] * BUCKET_CAP + base[bb[k]] + rank[k]] = rec[k];
}

// ---------------------------------------------------------------------------
// Kernel 2: XCD-local gather via real XCC_ID + work-stealing cursors
// (structure verified R8: gather dropped below 41 us). Finish: per-block
// atomicAdd into ws accumulator + last-block writes out[0] — removes the
// final_reduce dispatch and the d_out memset.
// ---------------------------------------------------------------------------
__device__ __forceinline__ void acc_u32(unsigned a, unsigned p, unsigned n, float& d)
{
    const vfloat2 a0 = __builtin_amdgcn_cvt_pk_f32_fp8(a, false);
    const vfloat2 a1 = __builtin_amdgcn_cvt_pk_f32_fp8(a, true);
    const vfloat2 p0 = __builtin_amdgcn_cvt_pk_f32_fp8(p, false);
    const vfloat2 p1 = __builtin_amdgcn_cvt_pk_f32_fp8(p, true);
    const vfloat2 n0 = __builtin_amdgcn_cvt_pk_f32_fp8(n, false);
    const vfloat2 n1 = __builtin_amdgcn_cvt_pk_f32_fp8(n, true);
    float t;
    t = a0.x - p0.x; d += t * t;  t = a0.x - n0.x; d -= t * t;
    t = a0.y - p0.y; d += t * t;  t = a0.y - n0.y; d -= t * t;
    t = a1.x - p1.x; d += t * t;  t = a1.x - n1.x; d -= t * t;
    t = a1.y - p1.y; d += t * t;  t = a1.y - n1.y; d -= t * t;
}

__device__ __forceinline__ void acc_quad(uint4 a, uint4 p, uint4 n, float& d)
{
    acc_u32(a.x, p.x, n.x, d);
    acc_u32(a.y, p.y, n.y, d);
    acc_u32(a.z, p.z, n.z, d);
    acc_u32(a.w, p.w, n.w, d);
}

__global__ __launch_bounds__(256) void triplet_gather_steal(
    const uint4* __restrict__ tq,   // (B*S) fp8 vectors, 16 uint4 each
    const uint4* __restrict__ tk,
    const uint4* __restrict__ recs,
    const unsigned* __restrict__ counts,  // 8 bucket fill counts
    unsigned* __restrict__ ccur,          // 8 consume cursors, stride 32 uints
    float* __restrict__ gacc,             // global fp32 accumulator (zeroed)
    unsigned* __restrict__ done,          // done-ticket (zeroed)
    float* __restrict__ out)
{
    const int t   = threadIdx.x;
    const int ol  = t & 7;           // lane within octet
    const int oct = t >> 3;          // octet id in block, 0..31

    unsigned xcc;
    asm volatile("s_getreg_b32 %0, hwreg(20, 0, 32)" : "=s"(xcc));  // HW_REG_XCC_ID
    const int myx = (int)(xcc & 7u);

    __shared__ unsigned sbase;
    float acc = 0.0f;

    for (int r = 0; r < 8; ++r) {                 // own bucket first, then sweep
        const int x = (myx + r) & 7;
        const unsigned cnt = counts[x];
        const uint4* __restrict__ brecs = recs + (size_t)x * BUCKET_CAP;

        for (;;) {
            __syncthreads();
            if (t == 0) sbase = atomicAdd(&ccur[x * 32], (unsigned)CHUNK);
            __syncthreads();
            const unsigned base = sbase;
            if (base >= cnt) break;

            const unsigned j = base + (unsigned)oct;
            if (j < cnt) {
                const uint4 rec = brecs[j];
                const size_t ab = (size_t)rec.x * 16;   // uint4 units
                const size_t pb = (size_t)rec.y * 16;
                const size_t nb = (size_t)rec.z * 16;

                const uint4 A0 = tq[ab + ol];
                const uint4 A1 = tq[ab + 8 + ol];
                const uint4 P0 = tk[pb + ol];
                const uint4 P1 = tk[pb + 8 + ol];
                const uint4 N0 = tk[nb + ol];
                const uint4 N1 = tk[nb + 8 + ol];

                float d = 0.0f;
                acc_quad(A0, P0, N0, d);
                acc_quad(A1, P1, N1, d);
#pragma unroll
                for (int m = 1; m < 8; m <<= 1) d += __shfl_xor(d, m, 64);
                if (ol == 0) acc += fmaxf(d + MARGIN_F, 0.0f);
            }
        }
    }

    // block reduce (non-zero only on ol==0 lanes)
#pragma unroll
    for (int m = 1; m < 64; m <<= 1) acc += __shfl_xor(acc, m, 64);
    __shared__ float wsum[4];
    if ((t & 63) == 0) wsum[t >> 6] = acc;
    __syncthreads();

    if (t == 0) {
        atomicAdd(gacc, wsum[0] + wsum[1] + wsum[2] + wsum[3]);
        __threadfence();                               // order gacc add before ticket
        const unsigned my = atomicAdd(done, 1u);
        if (my == GATHER_BLOCKS - 1) {                 // last block finishes
            const float total = atomicAdd(gacc, 0.0f); // coherent read at L2 point
            out[0] = total * (1.0f / (1e-6f + (float)NSAMP));
        }
    }
}

// ---------------------------------------------------------------------------
// Fallback (ws too small): direct strided gather in original layout.
// ---------------------------------------------------------------------------
__global__ __launch_bounds__(256) void triplet_direct(
    const float* __restrict__ q, const float* __restrict__ k,
    const int*  __restrict__ batch_idx,
    const int2* __restrict__ anchor_yx,
    const int2* __restrict__ pos_yx,
    const int2* __restrict__ neg_yx,
    float* __restrict__ out)
{
    const int lane   = threadIdx.x & 63;
    const int wid    = threadIdx.x >> 6;
    const int gwave  = blockIdx.x * 4 + wid;
    const int nwaves = gridDim.x * 4;

    float wsum = 0.0f;
    for (int i = gwave; i < NSAMP; i += nwaves) {
        const int  b  = batch_idx[i];
        const int2 ay = anchor_yx[i];
        const int2 py = pos_yx[i];
        const int2 ny = neg_yx[i];

        const size_t base = (size_t)b * NC * NS;
        const int sa = ay.x * FW + ay.y;
        const int sp = py.x * FW + py.y;
        const int sn = ny.x * FW + ny.y;

        float d = 0.0f;
#pragma unroll
        for (int kk = 0; kk < 4; ++kk) {
            const int c = lane + 64 * kk;
            const float av = q[base + (size_t)c * NS + sa];
            const float pv = k[base + (size_t)c * NS + sp];
            const float nv = k[base + (size_t)c * NS + sn];
            float t;
            t = av - pv; d += t * t;
            t = av - nv; d -= t * t;
        }
#pragma unroll
        for (int m = 1; m < 64; m <<= 1) d += __shfl_xor(d, m, 64);
        if (lane == 0) wsum += fmaxf(d + MARGIN_F, 0.0f);
    }

    __shared__ float bsum[4];
    if (lane == 0) bsum[wid] = wsum;
    __syncthreads();
    if (threadIdx.x == 0) {
        const float invN = 1.0f / (1e-6f + (float)NSAMP);
        atomicAdd(out, (bsum[0] + bsum[1] + bsum[2] + bsum[3]) * invN);
    }
}

extern "C" void kernel_launch(void* const* d_in, const int* in_sizes, int n_in,
                              void* d_out, int out_size, void* d_ws, size_t ws_size,
                              hipStream_t stream)
{
    const float* sketch = (const float*)d_in[0];
    const float* refk   = (const float*)d_in[1];
    const int*   bidx   = (const int*)d_in[2];
    const int2*  ayx    = (const int2*)d_in[3];
    const int2*  pyx    = (const int2*)d_in[4];
    const int2*  nyx    = (const int2*)d_in[5];
    float*       out    = (float*)d_out;

    const size_t tensor_elems = (size_t)NB * NC * NS;                    // 8M (8 MB fp8 each)
    const size_t recs_bytes   = (size_t)NB * BUCKET_CAP * sizeof(uint4); // 16 MB
    const size_t ctrl_uints   = 8 + 8 * 32 + 1 + 1;   // counts, cursors, done, acc
    const size_t need = 2 * tensor_elems + recs_bytes + ctrl_uints * 4;

    if (ws_size >= need) {
        unsigned char* tq = (unsigned char*)d_ws;
        unsigned char* tk = tq + tensor_elems;
        uint4* recs       = (uint4*)(tk + tensor_elems);
        unsigned* counts  = (unsigned*)((unsigned char*)recs + recs_bytes);
        unsigned* ccur    = counts + 8;
        unsigned* done    = ccur + 8 * 32;
        float*    gacc    = (float*)(done + 1);

        (void)hipMemsetAsync(counts, 0, ctrl_uints * sizeof(unsigned), stream);

        dim3 tgrid(NS / 64, NC / 64, 17);   // z<16: transpose; z==16: bucket
        transpose_bucket<<<tgrid, 256, 0, stream>>>(
            sketch, refk, tq, tk, bidx, ayx, pyx, nyx, recs, counts);

        triplet_gather_steal<<<GATHER_BLOCKS, 256, 0, stream>>>(
            (const uint4*)tq, (const uint4*)tk, recs, counts, ccur, gacc, done, out);
    } else {
        (void)hipMemsetAsync(out, 0, sizeof(float), stream);
        triplet_direct<<<4096, 256, 0, stream>>>(
            sketch, refk, bidx, ayx, pyx, nyx, out);
    }
}